// Round 1
// baseline (688.609 us; speedup 1.0000x reference)
//
#include <hip/hip_runtime.h>
#include <cstdint>
#include <cstddef>

#define N_NODES 100000
#define N_EDGES 1600000
#define N_GRAPHS 256
#define HID 128

#define SCHUNK 2048
#define SNB ((N_NODES + SCHUNK - 1) / SCHUNK)  // 49

static __device__ __forceinline__ float lrelu(float x) { return x >= 0.f ? x : 0.2f * x; }
static __device__ __forceinline__ float elu_f(float x) { return x > 0.f ? x : expm1f(x); }

// --- K1: cl1 = W1·al1, cr1 = W1·ar1 (layer-1 rank-1 collapse) ---
__global__ void k_prep(const float* __restrict__ W1, const float* __restrict__ al1,
                       const float* __restrict__ ar1, float* __restrict__ scal) {
    int l = threadIdx.x;  // 64 threads
    float pl = W1[l] * al1[l] + W1[l + 64] * al1[l + 64];
    float pr = W1[l] * ar1[l] + W1[l + 64] * ar1[l + 64];
    for (int m = 32; m >= 1; m >>= 1) { pl += __shfl_xor(pl, m); pr += __shfl_xor(pr, m); }
    if (l == 0) { scal[0] = pl; scal[1] = pr; }
}

// --- K2: in-degree ---
__global__ void k_deg(const int* __restrict__ dst, int* __restrict__ deg) {
    int i = blockIdx.x * blockDim.x + threadIdx.x;
    int st = gridDim.x * blockDim.x;
    for (; i < N_EDGES; i += st) atomicAdd(&deg[dst[i]], 1);
}

// --- K3: exclusive scan of deg -> offsets (3-kernel) ---
__global__ void k_scan_part(const int* __restrict__ deg, int* __restrict__ P) {
    __shared__ int sh[256];
    int base = blockIdx.x * SCHUNK + threadIdx.x * 8;
    int s = 0;
#pragma unroll
    for (int e = 0; e < 8; e++) { int idx = base + e; if (idx < N_NODES) s += deg[idx]; }
    sh[threadIdx.x] = s; __syncthreads();
    for (int d = 128; d >= 1; d >>= 1) {
        if (threadIdx.x < d) sh[threadIdx.x] += sh[threadIdx.x + d];
        __syncthreads();
    }
    if (threadIdx.x == 0) P[blockIdx.x] = sh[0];
}

__global__ void k_scan_p2(const int* __restrict__ P, int* __restrict__ P2, int* __restrict__ offs) {
    if (threadIdx.x == 0) {
        int run = 0;
        for (int b = 0; b < SNB; b++) { P2[b] = run; run += P[b]; }
        offs[N_NODES] = run;  // == N_EDGES
    }
}

__global__ void k_scan_final(const int* __restrict__ deg, const int* __restrict__ P2,
                             int* __restrict__ offs) {
    __shared__ int sh[256];
    int base = blockIdx.x * SCHUNK + threadIdx.x * 8;
    int loc[8]; int s = 0;
#pragma unroll
    for (int e = 0; e < 8; e++) {
        int idx = base + e;
        loc[e] = (idx < N_NODES) ? deg[idx] : 0;
        s += loc[e];
    }
    int own = s;
    sh[threadIdx.x] = s; __syncthreads();
    for (int d = 1; d < 256; d <<= 1) {
        int v = (threadIdx.x >= (unsigned)d) ? sh[threadIdx.x - d] : 0;
        __syncthreads();
        sh[threadIdx.x] += v;
        __syncthreads();
    }
    int run = P2[blockIdx.x] + sh[threadIdx.x] - own;  // exclusive base for this thread
#pragma unroll
    for (int e = 0; e < 8; e++) {
        int idx = base + e;
        if (idx < N_NODES) { offs[idx] = run; run += loc[e]; }
    }
}

// --- K4: CSR fill (src list grouped by dst) ---
__global__ void k_csr(const int* __restrict__ src, const int* __restrict__ dst,
                      const int* __restrict__ offs, int* __restrict__ fill,
                      int* __restrict__ csr_src) {
    int i = blockIdx.x * blockDim.x + threadIdx.x;
    int st = gridDim.x * blockDim.x;
    for (; i < N_EDGES; i += st) {
        int d = dst[i];
        int pos = offs[d] + atomicAdd(&fill[d], 1);
        csr_src[pos] = src[i];
    }
}

// --- K5: layer-1 attention -> per-node scalar t[i] = sum(alpha * indeg[src]) ---
__global__ void k_l1(const int* __restrict__ deg, const int* __restrict__ offs,
                     const int* __restrict__ csr_src, const float* __restrict__ scal,
                     float* __restrict__ t) {
    int i = blockIdx.x * blockDim.x + threadIdx.x;
    if (i >= N_NODES) return;
    float cl = scal[0], cr = scal[1];
    float eri = cr * (float)deg[i];
    int off = offs[i], end = offs[i + 1];
    float m = -INFINITY, den = 0.f, num = 0.f;
    for (int e = off; e < end; e++) {
        int s = csr_src[e];
        float ds = (float)deg[s];
        float e1 = lrelu(cl * ds + eri);
        if (e1 > m) { float c = expf(m - e1); den *= c; num *= c; m = e1; }
        float w = expf(e1 - m);
        den += w; num += w * ds;
    }
    t[i] = num / fmaxf(den, 1e-9f);
}

// --- K6: z2 = elu(t*W1+b1) @ W2 ; el2 = z2·al2 ; er2 = z2·ar2 ---
__global__ __launch_bounds__(256, 2) void k_gemm(
    const float* __restrict__ t, const float* __restrict__ W1, const float* __restrict__ b1,
    const float* __restrict__ W2, const float* __restrict__ al2, const float* __restrict__ ar2,
    float* __restrict__ z2, float* __restrict__ el2, float* __restrict__ er2) {
    __shared__ float W2s[HID * HID];
    __shared__ float W1s[HID], b1s[HID], al2s[HID], ar2s[HID];
    __shared__ float h1s[8][HID];
    for (int i = threadIdx.x; i < HID * HID / 4; i += 256)
        ((float4*)W2s)[i] = ((const float4*)W2)[i];
    if (threadIdx.x < HID) {
        W1s[threadIdx.x] = W1[threadIdx.x]; b1s[threadIdx.x] = b1[threadIdx.x];
        al2s[threadIdx.x] = al2[threadIdx.x]; ar2s[threadIdx.x] = ar2[threadIdx.x];
    }
    __syncthreads();
    int g = threadIdx.x >> 5;    // group 0..7, one node per 32-thread group
    int lt = threadIdx.x & 31;   // 0..31, 4 features each
    for (int i0 = blockIdx.x * 8; i0 < N_NODES; i0 += gridDim.x * 8) {
        int i = i0 + g;
        if (i < N_NODES) {
            float ti = t[i];
#pragma unroll
            for (int r = 0; r < 4; r++) {
                int k = 4 * lt + r;
                h1s[g][k] = elu_f(ti * W1s[k] + b1s[k]);  // same-wave LDS producer/consumer
            }
            float4 acc = {0.f, 0.f, 0.f, 0.f};
#pragma unroll 8
            for (int k = 0; k < HID; k++) {
                float h = h1s[g][k];                              // broadcast read
                float4 w = *(const float4*)&W2s[k * HID + 4 * lt]; // conflict-free b128
                acc.x += h * w.x; acc.y += h * w.y; acc.z += h * w.z; acc.w += h * w.w;
            }
            *(float4*)&z2[(size_t)i * HID + 4 * lt] = acc;
            float pl = acc.x * al2s[4 * lt] + acc.y * al2s[4 * lt + 1] +
                       acc.z * al2s[4 * lt + 2] + acc.w * al2s[4 * lt + 3];
            float pr = acc.x * ar2s[4 * lt] + acc.y * ar2s[4 * lt + 1] +
                       acc.z * ar2s[4 * lt + 2] + acc.w * ar2s[4 * lt + 3];
            for (int mm = 16; mm >= 1; mm >>= 1) { pl += __shfl_xor(pl, mm); pr += __shfl_xor(pr, mm); }
            if (lt == 0) { el2[i] = pl; er2[i] = pr; }
        }
    }
}

// --- K7: layer-2 attention + aggregation + bias + ELU -> h2 (heavy gather) ---
__global__ __launch_bounds__(256) void k_l2(
    const int* __restrict__ offs, const int* __restrict__ csr_src,
    const float* __restrict__ el2, const float* __restrict__ er2,
    const float* __restrict__ z2, const float* __restrict__ b2,
    float* __restrict__ h2) {
    int node = blockIdx.x * 4 + (threadIdx.x >> 6);  // one wave per node
    if (node >= N_NODES) return;
    int l = threadIdx.x & 63;  // 2 features per lane
    float eri = er2[node];
    int off = offs[node], end = offs[node + 1];
    float m = -INFINITY, den = 0.f, a0 = 0.f, a1 = 0.f;
    for (int e = off; e < end; e++) {
        int s = csr_src[e];
        float x = el2[s] + eri;
        float e2 = x >= 0.f ? x : 0.2f * x;
        if (e2 > m) {  // wave-uniform branch (online softmax rescale)
            float c = expf(m - e2);
            den *= c; a0 *= c; a1 *= c; m = e2;
        }
        float w = expf(e2 - m);
        den += w;
        float2 z = *(const float2*)&z2[(size_t)s * HID + 2 * l];
        a0 += w * z.x; a1 += w * z.y;
    }
    float r = 1.f / fmaxf(den, 1e-9f);
    float v0 = elu_f(a0 * r + b2[2 * l]);
    float v1 = elu_f(a1 * r + b2[2 * l + 1]);
    float2 o; o.x = v0; o.y = v1;
    *(float2*)&h2[(size_t)node * HID + 2 * l] = o;
}

// --- K8: mean-pool per graph (sorted graph_ids, binary-searched range) + classifier ---
static __device__ __forceinline__ int lower_bound_i(const int* a, int n, int v) {
    int lo = 0, hi = n;
    while (lo < hi) { int mid = (lo + hi) >> 1; if (a[mid] < v) lo = mid + 1; else hi = mid; }
    return lo;
}

__global__ void k_pool(const int* __restrict__ gids, const float* __restrict__ h2,
                       const float* __restrict__ Wc, const float* __restrict__ bc,
                       float* __restrict__ out) {
    int g = blockIdx.x;  // 0..255
    int lo = lower_bound_i(gids, N_NODES, g);
    int hi = lower_bound_i(gids, N_NODES, g + 1);
    int j = threadIdx.x;  // 128 threads, one feature each
    float s = 0.f;
    for (int n = lo; n < hi; n++) s += h2[(size_t)n * HID + j];
    float hg = s / fmaxf((float)(hi - lo), 1.f);
    float p0 = hg * Wc[j * 3 + 0];
    float p1 = hg * Wc[j * 3 + 1];
    float p2 = hg * Wc[j * 3 + 2];
    for (int mm = 32; mm >= 1; mm >>= 1) {
        p0 += __shfl_xor(p0, mm); p1 += __shfl_xor(p1, mm); p2 += __shfl_xor(p2, mm);
    }
    __shared__ float red[2][3];
    if ((threadIdx.x & 63) == 0) {
        int w = threadIdx.x >> 6;
        red[w][0] = p0; red[w][1] = p1; red[w][2] = p2;
    }
    __syncthreads();
    if (threadIdx.x < 3)
        out[g * 3 + threadIdx.x] = red[0][threadIdx.x] + red[1][threadIdx.x] + bc[threadIdx.x];
}

extern "C" void kernel_launch(void* const* d_in, const int* in_sizes, int n_in,
                              void* d_out, int out_size, void* d_ws, size_t ws_size,
                              hipStream_t stream) {
    (void)in_sizes; (void)n_in; (void)out_size; (void)ws_size;
    const int* edge_src = (const int*)d_in[0];
    const int* edge_dst = (const int*)d_in[1];
    const int* gids     = (const int*)d_in[2];
    const float* W1  = (const float*)d_in[3];
    const float* al1 = (const float*)d_in[4];
    const float* ar1 = (const float*)d_in[5];
    const float* b1  = (const float*)d_in[6];
    const float* W2  = (const float*)d_in[7];
    const float* al2 = (const float*)d_in[8];
    const float* ar2 = (const float*)d_in[9];
    const float* b2  = (const float*)d_in[10];
    const float* Wc  = (const float*)d_in[11];
    const float* bc  = (const float*)d_in[12];
    float* out = (float*)d_out;

    char* p = (char*)d_ws;
    auto alloc = [&](size_t bytes) -> char* {
        char* r = p;
        p += (bytes + 511) & ~(size_t)511;
        return r;
    };
    int*   deg  = (int*)alloc((size_t)N_NODES * 4);
    int*   fill = (int*)alloc((size_t)N_NODES * 4);
    int*   offs = (int*)alloc((size_t)(N_NODES + 1) * 4);
    int*   P    = (int*)alloc((size_t)SNB * 4);
    int*   P2   = (int*)alloc((size_t)SNB * 4);
    float* scal = (float*)alloc(64);
    int*   csr  = (int*)alloc((size_t)N_EDGES * 4);
    float* t    = (float*)alloc((size_t)N_NODES * 4);
    float* el2  = (float*)alloc((size_t)N_NODES * 4);
    float* er2  = (float*)alloc((size_t)N_NODES * 4);
    float* z2   = (float*)alloc((size_t)N_NODES * HID * 4);
    float* h2   = (float*)alloc((size_t)N_NODES * HID * 4);

    hipMemsetAsync(deg, 0, (size_t)N_NODES * 4, stream);
    hipMemsetAsync(fill, 0, (size_t)N_NODES * 4, stream);

    k_prep<<<1, 64, 0, stream>>>(W1, al1, ar1, scal);
    k_deg<<<2048, 256, 0, stream>>>(edge_dst, deg);
    k_scan_part<<<SNB, 256, 0, stream>>>(deg, P);
    k_scan_p2<<<1, 64, 0, stream>>>(P, P2, offs);
    k_scan_final<<<SNB, 256, 0, stream>>>(deg, P2, offs);
    k_csr<<<2048, 256, 0, stream>>>(edge_src, edge_dst, offs, fill, csr);
    k_l1<<<(N_NODES + 255) / 256, 256, 0, stream>>>(deg, offs, csr, scal, t);
    k_gemm<<<512, 256, 0, stream>>>(t, W1, b1, W2, al2, ar2, z2, el2, er2);
    k_l2<<<(N_NODES + 3) / 4, 256, 0, stream>>>(offs, csr, el2, er2, z2, b2, h2);
    k_pool<<<N_GRAPHS, 128, 0, stream>>>(gids, h2, Wc, bc, out);
}

// Round 3
// 489.529 us; speedup vs baseline: 1.4067x; 1.4067x over previous
//
#include <hip/hip_runtime.h>
#include <cstdint>
#include <cstddef>

#define N_NODES 100000
#define N_EDGES 1600000
#define N_GRAPHS 256
#define HID 128

#define SCHUNK 2048
#define SNB ((N_NODES + SCHUNK - 1) / SCHUNK)  // 49

static __device__ __forceinline__ float lrelu(float x) { return x >= 0.f ? x : 0.2f * x; }
static __device__ __forceinline__ float elu_f(float x) { return x > 0.f ? x : expm1f(x); }
static __device__ __forceinline__ unsigned f2bf(float x) {  // RNE bf16 (as uint16 in low bits)
    union { float f; unsigned u; } v; v.f = x;
    return (v.u + 0x7FFFu + ((v.u >> 16) & 1u)) >> 16;
}
static __device__ __forceinline__ float bf_lo(unsigned u) { return __uint_as_float(u << 16); }
static __device__ __forceinline__ float bf_hi(unsigned u) { return __uint_as_float(u & 0xFFFF0000u); }

// --- K1: cl1 = W1·al1, cr1 = W1·ar1 (layer-1 rank-1 collapse) ---
__global__ void k_prep(const float* __restrict__ W1, const float* __restrict__ al1,
                       const float* __restrict__ ar1, float* __restrict__ scal) {
    int l = threadIdx.x;  // 64 threads
    float pl = W1[l] * al1[l] + W1[l + 64] * al1[l + 64];
    float pr = W1[l] * ar1[l] + W1[l + 64] * ar1[l + 64];
    for (int m = 32; m >= 1; m >>= 1) { pl += __shfl_xor(pl, m); pr += __shfl_xor(pr, m); }
    if (l == 0) { scal[0] = pl; scal[1] = pr; }
}

// --- K2: in-degree ---
__global__ void k_deg(const int* __restrict__ dst, int* __restrict__ deg) {
    int i = blockIdx.x * blockDim.x + threadIdx.x;
    int st = gridDim.x * blockDim.x;
    for (; i < N_EDGES; i += st) atomicAdd(&deg[dst[i]], 1);
}

// --- K3: exclusive scan of deg -> offsets ---
__global__ void k_scan_part(const int* __restrict__ deg, int* __restrict__ P) {
    __shared__ int sh[256];
    int base = blockIdx.x * SCHUNK + threadIdx.x * 8;
    int s = 0;
#pragma unroll
    for (int e = 0; e < 8; e++) { int idx = base + e; if (idx < N_NODES) s += deg[idx]; }
    sh[threadIdx.x] = s; __syncthreads();
    for (int d = 128; d >= 1; d >>= 1) {
        if (threadIdx.x < d) sh[threadIdx.x] += sh[threadIdx.x + d];
        __syncthreads();
    }
    if (threadIdx.x == 0) P[blockIdx.x] = sh[0];
}

__global__ void k_scan_p2(const int* __restrict__ P, int* __restrict__ P2, int* __restrict__ offs) {
    if (threadIdx.x == 0) {
        int run = 0;
        for (int b = 0; b < SNB; b++) { P2[b] = run; run += P[b]; }
        offs[N_NODES] = run;
    }
}

__global__ void k_scan_final(const int* __restrict__ deg, const int* __restrict__ P2,
                             int* __restrict__ offs) {
    __shared__ int sh[256];
    int base = blockIdx.x * SCHUNK + threadIdx.x * 8;
    int loc[8]; int s = 0;
#pragma unroll
    for (int e = 0; e < 8; e++) {
        int idx = base + e;
        loc[e] = (idx < N_NODES) ? deg[idx] : 0;
        s += loc[e];
    }
    int own = s;
    sh[threadIdx.x] = s; __syncthreads();
    for (int d = 1; d < 256; d <<= 1) {
        int v = (threadIdx.x >= (unsigned)d) ? sh[threadIdx.x - d] : 0;
        __syncthreads();
        sh[threadIdx.x] += v;
        __syncthreads();
    }
    int run = P2[blockIdx.x] + sh[threadIdx.x] - own;
#pragma unroll
    for (int e = 0; e < 8; e++) {
        int idx = base + e;
        if (idx < N_NODES) { offs[idx] = run; run += loc[e]; }
    }
}

// --- K4: CSR fill ---
__global__ void k_csr(const int* __restrict__ src, const int* __restrict__ dst,
                      const int* __restrict__ offs, int* __restrict__ fill,
                      int* __restrict__ csr_src) {
    int i = blockIdx.x * blockDim.x + threadIdx.x;
    int st = gridDim.x * blockDim.x;
    for (; i < N_EDGES; i += st) {
        int d = dst[i];
        int pos = offs[d] + atomicAdd(&fill[d], 1);
        csr_src[pos] = src[i];
    }
}

// --- K5: layer-1 attention -> t[i] (wave per node, lane-parallel edges) ---
__global__ __launch_bounds__(256) void k_l1(const int* __restrict__ deg, const int* __restrict__ offs,
                                            const int* __restrict__ csr_src, const float* __restrict__ scal,
                                            float* __restrict__ t) {
    int node = blockIdx.x * 4 + (threadIdx.x >> 6);
    if (node >= N_NODES) return;
    int l = threadIdx.x & 63;
    float cl = scal[0], cr = scal[1];
    float eri = cr * (float)deg[node];
    int off = offs[node], end = offs[node + 1];
    float m = -INFINITY, den = 0.f, num = 0.f;
    for (int e = off + l; e < end; e += 64) {
        int s = csr_src[e];
        float ds = (float)deg[s];
        float e1 = lrelu(cl * ds + eri);
        if (e1 > m) { float c = __expf(m - e1); den *= c; num *= c; m = e1; }
        float w = __expf(e1 - m);
        den += w; num += w * ds;
    }
    // merge online-softmax states across 64 lanes
    for (int st = 1; st < 64; st <<= 1) {
        float mo = __shfl_xor(m, st);
        float dn = __shfl_xor(den, st);
        float no = __shfl_xor(num, st);
        float mn = fmaxf(m, mo);
        float sa = (m  > -1e37f) ? __expf(m  - mn) : 0.f;
        float sb = (mo > -1e37f) ? __expf(mo - mn) : 0.f;
        den = den * sa + dn * sb;
        num = num * sa + no * sb;
        m = mn;
    }
    if (l == 0) t[node] = num / fmaxf(den, 1e-9f);
}

// --- K6: z2 = elu(t*W1+b1) @ W2 (bf16 out) ; el2/er2 from fp32 acc ---
// 8 groups of 32 lanes; each group computes 8 nodes; 8-node register blocking per W2 load.
__global__ __launch_bounds__(256, 2) void k_gemm(
    const float* __restrict__ t, const float* __restrict__ W1, const float* __restrict__ b1,
    const float* __restrict__ W2, const float* __restrict__ al2, const float* __restrict__ ar2,
    unsigned* __restrict__ zb, float* __restrict__ el2, float* __restrict__ er2) {
    __shared__ float h1s[8][8][HID];
    __shared__ float W1s[HID], b1s[HID], al2s[HID], ar2s[HID];
    if (threadIdx.x < HID) {
        W1s[threadIdx.x] = W1[threadIdx.x]; b1s[threadIdx.x] = b1[threadIdx.x];
        al2s[threadIdx.x] = al2[threadIdx.x]; ar2s[threadIdx.x] = ar2[threadIdx.x];
    }
    __syncthreads();
    int g = threadIdx.x >> 5;
    int lt = threadIdx.x & 31;
    const float4* W2v = (const float4*)W2;
    for (int i0 = blockIdx.x * 64; i0 < N_NODES; i0 += gridDim.x * 64) {
        int ibase = i0 + g * 8;
        // stage h1 for this group's 8 nodes (float4 LDS writes)
        for (int n = 0; n < 8; n++) {
            int i = ibase + n;
            if (i < N_NODES) {
                float ti = t[i];
                float4 hv;
                hv.x = elu_f(ti * W1s[4 * lt + 0] + b1s[4 * lt + 0]);
                hv.y = elu_f(ti * W1s[4 * lt + 1] + b1s[4 * lt + 1]);
                hv.z = elu_f(ti * W1s[4 * lt + 2] + b1s[4 * lt + 2]);
                hv.w = elu_f(ti * W1s[4 * lt + 3] + b1s[4 * lt + 3]);
                *(float4*)&h1s[g][n][4 * lt] = hv;
            }
        }
        __syncthreads();
        float4 acc[8];
#pragma unroll
        for (int n = 0; n < 8; n++) acc[n] = make_float4(0.f, 0.f, 0.f, 0.f);
#pragma unroll 4
        for (int k = 0; k < HID; k++) {
            float4 w = W2v[k * 32 + lt];  // L2-resident stream, shared by all waves
#pragma unroll
            for (int n = 0; n < 8; n++) {
                float h = h1s[g][n][k];  // LDS broadcast
                acc[n].x += h * w.x; acc[n].y += h * w.y;
                acc[n].z += h * w.z; acc[n].w += h * w.w;
            }
        }
#pragma unroll
        for (int n = 0; n < 8; n++) {
            int i = ibase + n;
            if (i < N_NODES) {
                float4 a = acc[n];
                uint2 st;
                st.x = f2bf(a.x) | (f2bf(a.y) << 16);
                st.y = f2bf(a.z) | (f2bf(a.w) << 16);
                *(uint2*)&zb[(size_t)i * 64 + 2 * lt] = st;
                float pl = a.x * al2s[4 * lt] + a.y * al2s[4 * lt + 1] +
                           a.z * al2s[4 * lt + 2] + a.w * al2s[4 * lt + 3];
                float pr = a.x * ar2s[4 * lt] + a.y * ar2s[4 * lt + 1] +
                           a.z * ar2s[4 * lt + 2] + a.w * ar2s[4 * lt + 3];
                for (int mm = 16; mm >= 1; mm >>= 1) { pl += __shfl_xor(pl, mm); pr += __shfl_xor(pr, mm); }
                if (lt == 0) { el2[i] = pl; er2[i] = pr; }
            }
        }
        __syncthreads();
    }
}

// --- K7a: layer-2 attention weights alpha[e] (wave per node, lane-parallel) ---
__global__ __launch_bounds__(256) void k_att2(
    const int* __restrict__ offs, const int* __restrict__ csr_src,
    const float* __restrict__ el2, const float* __restrict__ er2,
    float* __restrict__ alpha) {
    int node = blockIdx.x * 4 + (threadIdx.x >> 6);
    if (node >= N_NODES) return;
    int l = threadIdx.x & 63;
    float eri = er2[node];
    int off = offs[node], end = offs[node + 1];
    float m = -INFINITY, den = 0.f;
    for (int e = off + l; e < end; e += 64) {
        int s = csr_src[e];
        float x = el2[s] + eri;
        float e2 = x >= 0.f ? x : 0.2f * x;
        if (e2 > m) { den *= __expf(m - e2); m = e2; }
        den += __expf(e2 - m);
    }
    for (int st = 1; st < 64; st <<= 1) {
        float mo = __shfl_xor(m, st);
        float dn = __shfl_xor(den, st);
        float mn = fmaxf(m, mo);
        float sa = (m  > -1e37f) ? __expf(m  - mn) : 0.f;
        float sb = (mo > -1e37f) ? __expf(mo - mn) : 0.f;
        den = den * sa + dn * sb;
        m = mn;
    }
    float rden = 1.f / fmaxf(den, 1e-9f);
    for (int e = off + l; e < end; e += 64) {  // recompute (L1-hot) and normalize
        int s = csr_src[e];
        float x = el2[s] + eri;
        float e2 = x >= 0.f ? x : 0.2f * x;
        alpha[e] = __expf(e2 - m) * rden;
    }
}

// --- K7b: weighted gather h2 = elu(sum alpha*z + b2); no cross-edge deps, 4x unroll ---
__global__ __launch_bounds__(256) void k_agg2(
    const int* __restrict__ offs, const int* __restrict__ csr_src,
    const float* __restrict__ alpha, const unsigned* __restrict__ zb,
    const float* __restrict__ b2, float* __restrict__ h2) {
    int node = blockIdx.x * 4 + (threadIdx.x >> 6);
    if (node >= N_NODES) return;
    int l = threadIdx.x & 63;  // 2 features per lane (one packed bf16x2 word)
    int off = offs[node], end = offs[node + 1];
    float a0 = 0.f, a1 = 0.f;
    int e = off;
    for (; e + 4 <= end; e += 4) {
        int s0 = csr_src[e], s1 = csr_src[e + 1], s2 = csr_src[e + 2], s3 = csr_src[e + 3];
        float w0 = alpha[e], w1 = alpha[e + 1], w2 = alpha[e + 2], w3 = alpha[e + 3];
        unsigned z0 = zb[(size_t)s0 * 64 + l];
        unsigned z1 = zb[(size_t)s1 * 64 + l];
        unsigned z2 = zb[(size_t)s2 * 64 + l];
        unsigned z3 = zb[(size_t)s3 * 64 + l];
        a0 += w0 * bf_lo(z0) + w1 * bf_lo(z1) + w2 * bf_lo(z2) + w3 * bf_lo(z3);
        a1 += w0 * bf_hi(z0) + w1 * bf_hi(z1) + w2 * bf_hi(z2) + w3 * bf_hi(z3);
    }
    for (; e < end; e++) {
        int s = csr_src[e];
        float w = alpha[e];
        unsigned z = zb[(size_t)s * 64 + l];
        a0 += w * bf_lo(z);
        a1 += w * bf_hi(z);
    }
    float2 bb = *(const float2*)&b2[2 * l];
    float2 o;
    o.x = elu_f(a0 + bb.x);
    o.y = elu_f(a1 + bb.y);
    *(float2*)&h2[(size_t)node * HID + 2 * l] = o;
}

// --- K8: mean-pool + classifier ---
static __device__ __forceinline__ int lower_bound_i(const int* a, int n, int v) {
    int lo = 0, hi = n;
    while (lo < hi) { int mid = (lo + hi) >> 1; if (a[mid] < v) lo = mid + 1; else hi = mid; }
    return lo;
}

__global__ __launch_bounds__(1024) void k_pool(const int* __restrict__ gids, const float* __restrict__ h2,
                                               const float* __restrict__ Wc, const float* __restrict__ bc,
                                               float* __restrict__ out) {
    int g = blockIdx.x;
    int lo = lower_bound_i(gids, N_NODES, g);
    int hi = lower_bound_i(gids, N_NODES, g + 1);
    int j = threadIdx.x & 127;   // feature
    int nn = threadIdx.x >> 7;   // node-slot 0..7
    float s = 0.f;
    for (int n = lo + nn; n < hi; n += 8) s += h2[(size_t)n * HID + j];
    __shared__ float red[1024];
    red[threadIdx.x] = s;
    __syncthreads();
    __shared__ float red2[2][3];
    if (threadIdx.x < 128) {
        float hg = 0.f;
#pragma unroll
        for (int q = 0; q < 8; q++) hg += red[q * 128 + j];
        hg /= fmaxf((float)(hi - lo), 1.f);
        float p0 = hg * Wc[j * 3 + 0];
        float p1 = hg * Wc[j * 3 + 1];
        float p2 = hg * Wc[j * 3 + 2];
        for (int mm = 32; mm >= 1; mm >>= 1) {
            p0 += __shfl_xor(p0, mm); p1 += __shfl_xor(p1, mm); p2 += __shfl_xor(p2, mm);
        }
        if ((threadIdx.x & 63) == 0) {
            int w = threadIdx.x >> 6;
            red2[w][0] = p0; red2[w][1] = p1; red2[w][2] = p2;
        }
    }
    __syncthreads();
    if (threadIdx.x < 3)
        out[g * 3 + threadIdx.x] = red2[0][threadIdx.x] + red2[1][threadIdx.x] + bc[threadIdx.x];
}

extern "C" void kernel_launch(void* const* d_in, const int* in_sizes, int n_in,
                              void* d_out, int out_size, void* d_ws, size_t ws_size,
                              hipStream_t stream) {
    (void)in_sizes; (void)n_in; (void)out_size; (void)ws_size;
    const int* edge_src = (const int*)d_in[0];
    const int* edge_dst = (const int*)d_in[1];
    const int* gids     = (const int*)d_in[2];
    const float* W1  = (const float*)d_in[3];
    const float* al1 = (const float*)d_in[4];
    const float* ar1 = (const float*)d_in[5];
    const float* b1  = (const float*)d_in[6];
    const float* W2  = (const float*)d_in[7];
    const float* al2 = (const float*)d_in[8];
    const float* ar2 = (const float*)d_in[9];
    const float* b2  = (const float*)d_in[10];
    const float* Wc  = (const float*)d_in[11];
    const float* bc  = (const float*)d_in[12];
    float* out = (float*)d_out;

    char* p = (char*)d_ws;
    auto alloc = [&](size_t bytes) -> char* {
        char* r = p;
        p += (bytes + 511) & ~(size_t)511;
        return r;
    };
    int*      deg   = (int*)alloc((size_t)N_NODES * 4);
    int*      fill  = (int*)alloc((size_t)N_NODES * 4);
    int*      offs  = (int*)alloc((size_t)(N_NODES + 1) * 4);
    int*      P     = (int*)alloc((size_t)SNB * 4);
    int*      P2    = (int*)alloc((size_t)SNB * 4);
    float*    scal  = (float*)alloc(64);
    int*      csr   = (int*)alloc((size_t)N_EDGES * 4);
    float*    t     = (float*)alloc((size_t)N_NODES * 4);
    float*    el2   = (float*)alloc((size_t)N_NODES * 4);
    float*    er2   = (float*)alloc((size_t)N_NODES * 4);
    float*    al_e  = (float*)alloc((size_t)N_EDGES * 4);
    unsigned* zb    = (unsigned*)alloc((size_t)N_NODES * 64 * 4);  // bf16x2 packed
    float*    h2    = (float*)alloc((size_t)N_NODES * HID * 4);

    hipMemsetAsync(deg, 0, (size_t)N_NODES * 4, stream);
    hipMemsetAsync(fill, 0, (size_t)N_NODES * 4, stream);

    k_prep<<<1, 64, 0, stream>>>(W1, al1, ar1, scal);
    k_deg<<<2048, 256, 0, stream>>>(edge_dst, deg);
    k_scan_part<<<SNB, 256, 0, stream>>>(deg, P);
    k_scan_p2<<<1, 64, 0, stream>>>(P, P2, offs);
    k_scan_final<<<SNB, 256, 0, stream>>>(deg, P2, offs);
    k_csr<<<2048, 256, 0, stream>>>(edge_src, edge_dst, offs, fill, csr);
    k_l1<<<(N_NODES + 3) / 4, 256, 0, stream>>>(deg, offs, csr, scal, t);
    k_gemm<<<(N_NODES + 63) / 64, 256, 0, stream>>>(t, W1, b1, W2, al2, ar2, zb, el2, er2);
    k_att2<<<(N_NODES + 3) / 4, 256, 0, stream>>>(offs, csr, el2, er2, al_e);
    k_agg2<<<(N_NODES + 3) / 4, 256, 0, stream>>>(offs, csr, al_e, zb, b2, h2);
    k_pool<<<N_GRAPHS, 1024, 0, stream>>>(gids, h2, Wc, bc, out);
}

// Round 4
// 403.782 us; speedup vs baseline: 1.7054x; 1.2124x over previous
//
#include <hip/hip_runtime.h>
#include <cstdint>
#include <cstddef>

#define N_NODES 100000
#define N_EDGES 1600000
#define N_GRAPHS 256
#define HID 128
#define NCLASS 8

#define SCHUNK 2048
#define SNB ((N_NODES + SCHUNK - 1) / SCHUNK)  // 49

static __device__ __forceinline__ float lrelu(float x) { return x >= 0.f ? x : 0.2f * x; }
static __device__ __forceinline__ float elu_f(float x) { return x > 0.f ? x : expm1f(x); }
static __device__ __forceinline__ unsigned f2bf(float x) {  // RNE bf16 (as uint16 in low bits)
    union { float f; unsigned u; } v; v.f = x;
    return (v.u + 0x7FFFu + ((v.u >> 16) & 1u)) >> 16;
}
static __device__ __forceinline__ float bf_lo(unsigned u) { return __uint_as_float(u << 16); }
static __device__ __forceinline__ float bf_hi(unsigned u) { return __uint_as_float(u & 0xFFFF0000u); }

// --- K1: cl1 = W1·al1, cr1 = W1·ar1 (layer-1 rank-1 collapse) ---
__global__ void k_prep(const float* __restrict__ W1, const float* __restrict__ al1,
                       const float* __restrict__ ar1, float* __restrict__ scal) {
    int l = threadIdx.x;  // 64 threads
    float pl = W1[l] * al1[l] + W1[l + 64] * al1[l + 64];
    float pr = W1[l] * ar1[l] + W1[l + 64] * ar1[l + 64];
    for (int m = 32; m >= 1; m >>= 1) { pl += __shfl_xor(pl, m); pr += __shfl_xor(pr, m); }
    if (l == 0) { scal[0] = pl; scal[1] = pr; }
}

// --- K2: degree count into 8 privatized replicas + per-edge rank (ONE atomic pass) ---
// class (i>>8)&7 is constant per 256-thread block => concurrent blocks hit different replicas.
__global__ void k_degrank(const int* __restrict__ dst, int* __restrict__ dr,
                          int* __restrict__ rank) {
    int i = blockIdx.x * blockDim.x + threadIdx.x;
    int st = gridDim.x * blockDim.x;
    for (; i < N_EDGES; i += st) {
        int cls = (i >> 8) & (NCLASS - 1);
        rank[i] = atomicAdd(&dr[cls * N_NODES + dst[i]], 1);
    }
}

// --- K2b: total degree = sum of replicas ---
__global__ void k_sum(const int* __restrict__ dr, int* __restrict__ deg) {
    int d = blockIdx.x * blockDim.x + threadIdx.x;
    if (d < N_NODES) {
        int s = 0;
#pragma unroll
        for (int r = 0; r < NCLASS; r++) s += dr[r * N_NODES + d];
        deg[d] = s;
    }
}

// --- K3: exclusive scan of deg -> offsets ---
__global__ void k_scan_part(const int* __restrict__ deg, int* __restrict__ P) {
    __shared__ int sh[256];
    int base = blockIdx.x * SCHUNK + threadIdx.x * 8;
    int s = 0;
#pragma unroll
    for (int e = 0; e < 8; e++) { int idx = base + e; if (idx < N_NODES) s += deg[idx]; }
    sh[threadIdx.x] = s; __syncthreads();
    for (int d = 128; d >= 1; d >>= 1) {
        if (threadIdx.x < d) sh[threadIdx.x] += sh[threadIdx.x + d];
        __syncthreads();
    }
    if (threadIdx.x == 0) P[blockIdx.x] = sh[0];
}

__global__ void k_scan_p2(const int* __restrict__ P, int* __restrict__ P2, int* __restrict__ offs) {
    if (threadIdx.x == 0) {
        int run = 0;
        for (int b = 0; b < SNB; b++) { P2[b] = run; run += P[b]; }
        offs[N_NODES] = run;
    }
}

__global__ void k_scan_final(const int* __restrict__ deg, const int* __restrict__ P2,
                             int* __restrict__ offs) {
    __shared__ int sh[256];
    int base = blockIdx.x * SCHUNK + threadIdx.x * 8;
    int loc[8]; int s = 0;
#pragma unroll
    for (int e = 0; e < 8; e++) {
        int idx = base + e;
        loc[e] = (idx < N_NODES) ? deg[idx] : 0;
        s += loc[e];
    }
    int own = s;
    sh[threadIdx.x] = s; __syncthreads();
    for (int d = 1; d < 256; d <<= 1) {
        int v = (threadIdx.x >= (unsigned)d) ? sh[threadIdx.x - d] : 0;
        __syncthreads();
        sh[threadIdx.x] += v;
        __syncthreads();
    }
    int run = P2[blockIdx.x] + sh[threadIdx.x] - own;
#pragma unroll
    for (int e = 0; e < 8; e++) {
        int idx = base + e;
        if (idx < N_NODES) { offs[idx] = run; run += loc[e]; }
    }
}

// --- K3b: per-class base offsets (prefix over replicas within each node) ---
__global__ void k_base(const int* __restrict__ dr, const int* __restrict__ offs,
                       int* __restrict__ base) {
    int d = blockIdx.x * blockDim.x + threadIdx.x;
    if (d < N_NODES) {
        int run = offs[d];
#pragma unroll
        for (int r = 0; r < NCLASS; r++) { base[r * N_NODES + d] = run; run += dr[r * N_NODES + d]; }
    }
}

// --- K4: CSR fill — NO atomics (position = class base + saved rank) ---
__global__ void k_fill(const int* __restrict__ src, const int* __restrict__ dst,
                       const int* __restrict__ base, const int* __restrict__ rank,
                       int* __restrict__ csr) {
    int i = blockIdx.x * blockDim.x + threadIdx.x;
    int st = gridDim.x * blockDim.x;
    for (; i < N_EDGES; i += st) {
        int cls = (i >> 8) & (NCLASS - 1);
        int pos = base[cls * N_NODES + dst[i]] + rank[i];
        csr[pos] = src[i];
    }
}

// --- K5: layer-1 attention -> t[i] (wave per node, lane-parallel edges) ---
__global__ __launch_bounds__(256) void k_l1(const int* __restrict__ deg, const int* __restrict__ offs,
                                            const int* __restrict__ csr_src, const float* __restrict__ scal,
                                            float* __restrict__ t) {
    int node = blockIdx.x * 4 + (threadIdx.x >> 6);
    if (node >= N_NODES) return;
    int l = threadIdx.x & 63;
    float cl = scal[0], cr = scal[1];
    float eri = cr * (float)deg[node];
    int off = offs[node], end = offs[node + 1];
    float m = -INFINITY, den = 0.f, num = 0.f;
    for (int e = off + l; e < end; e += 64) {
        int s = csr_src[e];
        float ds = (float)deg[s];
        float e1 = lrelu(cl * ds + eri);
        if (e1 > m) { float c = __expf(m - e1); den *= c; num *= c; m = e1; }
        float w = __expf(e1 - m);
        den += w; num += w * ds;
    }
    // merge online-softmax states across 64 lanes
    for (int st = 1; st < 64; st <<= 1) {
        float mo = __shfl_xor(m, st);
        float dn = __shfl_xor(den, st);
        float no = __shfl_xor(num, st);
        float mn = fmaxf(m, mo);
        float sa = (m  > -1e37f) ? __expf(m  - mn) : 0.f;
        float sb = (mo > -1e37f) ? __expf(mo - mn) : 0.f;
        den = den * sa + dn * sb;
        num = num * sa + no * sb;
        m = mn;
    }
    if (l == 0) t[node] = num / fmaxf(den, 1e-9f);
}

// --- K6: z2 = elu(t*W1+b1) @ W2 (bf16 out) ; el2/er2 from fp32 acc ---
__global__ __launch_bounds__(256, 2) void k_gemm(
    const float* __restrict__ t, const float* __restrict__ W1, const float* __restrict__ b1,
    const float* __restrict__ W2, const float* __restrict__ al2, const float* __restrict__ ar2,
    unsigned* __restrict__ zb, float* __restrict__ el2, float* __restrict__ er2) {
    __shared__ float h1s[8][8][HID];
    __shared__ float W1s[HID], b1s[HID], al2s[HID], ar2s[HID];
    if (threadIdx.x < HID) {
        W1s[threadIdx.x] = W1[threadIdx.x]; b1s[threadIdx.x] = b1[threadIdx.x];
        al2s[threadIdx.x] = al2[threadIdx.x]; ar2s[threadIdx.x] = ar2[threadIdx.x];
    }
    __syncthreads();
    int g = threadIdx.x >> 5;
    int lt = threadIdx.x & 31;
    const float4* W2v = (const float4*)W2;
    for (int i0 = blockIdx.x * 64; i0 < N_NODES; i0 += gridDim.x * 64) {
        int ibase = i0 + g * 8;
        for (int n = 0; n < 8; n++) {
            int i = ibase + n;
            if (i < N_NODES) {
                float ti = t[i];
                float4 hv;
                hv.x = elu_f(ti * W1s[4 * lt + 0] + b1s[4 * lt + 0]);
                hv.y = elu_f(ti * W1s[4 * lt + 1] + b1s[4 * lt + 1]);
                hv.z = elu_f(ti * W1s[4 * lt + 2] + b1s[4 * lt + 2]);
                hv.w = elu_f(ti * W1s[4 * lt + 3] + b1s[4 * lt + 3]);
                *(float4*)&h1s[g][n][4 * lt] = hv;
            }
        }
        __syncthreads();
        float4 acc[8];
#pragma unroll
        for (int n = 0; n < 8; n++) acc[n] = make_float4(0.f, 0.f, 0.f, 0.f);
#pragma unroll 4
        for (int k = 0; k < HID; k++) {
            float4 w = W2v[k * 32 + lt];  // L2-resident stream, shared by all waves
#pragma unroll
            for (int n = 0; n < 8; n++) {
                float h = h1s[g][n][k];  // LDS broadcast
                acc[n].x += h * w.x; acc[n].y += h * w.y;
                acc[n].z += h * w.z; acc[n].w += h * w.w;
            }
        }
#pragma unroll
        for (int n = 0; n < 8; n++) {
            int i = ibase + n;
            if (i < N_NODES) {
                float4 a = acc[n];
                uint2 st;
                st.x = f2bf(a.x) | (f2bf(a.y) << 16);
                st.y = f2bf(a.z) | (f2bf(a.w) << 16);
                *(uint2*)&zb[(size_t)i * 64 + 2 * lt] = st;
                float pl = a.x * al2s[4 * lt] + a.y * al2s[4 * lt + 1] +
                           a.z * al2s[4 * lt + 2] + a.w * al2s[4 * lt + 3];
                float pr = a.x * ar2s[4 * lt] + a.y * ar2s[4 * lt + 1] +
                           a.z * ar2s[4 * lt + 2] + a.w * ar2s[4 * lt + 3];
                for (int mm = 16; mm >= 1; mm >>= 1) { pl += __shfl_xor(pl, mm); pr += __shfl_xor(pr, mm); }
                if (lt == 0) { el2[i] = pl; er2[i] = pr; }
            }
        }
        __syncthreads();
    }
}

// --- K7a: layer-2 attention weights alpha[e] (wave per node, lane-parallel) ---
__global__ __launch_bounds__(256) void k_att2(
    const int* __restrict__ offs, const int* __restrict__ csr_src,
    const float* __restrict__ el2, const float* __restrict__ er2,
    float* __restrict__ alpha) {
    int node = blockIdx.x * 4 + (threadIdx.x >> 6);
    if (node >= N_NODES) return;
    int l = threadIdx.x & 63;
    float eri = er2[node];
    int off = offs[node], end = offs[node + 1];
    float m = -INFINITY, den = 0.f;
    for (int e = off + l; e < end; e += 64) {
        int s = csr_src[e];
        float x = el2[s] + eri;
        float e2 = x >= 0.f ? x : 0.2f * x;
        if (e2 > m) { den *= __expf(m - e2); m = e2; }
        den += __expf(e2 - m);
    }
    for (int st = 1; st < 64; st <<= 1) {
        float mo = __shfl_xor(m, st);
        float dn = __shfl_xor(den, st);
        float mn = fmaxf(m, mo);
        float sa = (m  > -1e37f) ? __expf(m  - mn) : 0.f;
        float sb = (mo > -1e37f) ? __expf(mo - mn) : 0.f;
        den = den * sa + dn * sb;
        m = mn;
    }
    float rden = 1.f / fmaxf(den, 1e-9f);
    for (int e = off + l; e < end; e += 64) {  // recompute (L1-hot) and normalize
        int s = csr_src[e];
        float x = el2[s] + eri;
        float e2 = x >= 0.f ? x : 0.2f * x;
        alpha[e] = __expf(e2 - m) * rden;
    }
}

// --- K7b: weighted gather h2 = elu(sum alpha*z + b2); no cross-edge deps, 4x unroll ---
__global__ __launch_bounds__(256) void k_agg2(
    const int* __restrict__ offs, const int* __restrict__ csr_src,
    const float* __restrict__ alpha, const unsigned* __restrict__ zb,
    const float* __restrict__ b2, float* __restrict__ h2) {
    int node = blockIdx.x * 4 + (threadIdx.x >> 6);
    if (node >= N_NODES) return;
    int l = threadIdx.x & 63;  // 2 features per lane (one packed bf16x2 word)
    int off = offs[node], end = offs[node + 1];
    float a0 = 0.f, a1 = 0.f;
    int e = off;
    for (; e + 4 <= end; e += 4) {
        int s0 = csr_src[e], s1 = csr_src[e + 1], s2 = csr_src[e + 2], s3 = csr_src[e + 3];
        float w0 = alpha[e], w1 = alpha[e + 1], w2 = alpha[e + 2], w3 = alpha[e + 3];
        unsigned z0 = zb[(size_t)s0 * 64 + l];
        unsigned z1 = zb[(size_t)s1 * 64 + l];
        unsigned z2 = zb[(size_t)s2 * 64 + l];
        unsigned z3 = zb[(size_t)s3 * 64 + l];
        a0 += w0 * bf_lo(z0) + w1 * bf_lo(z1) + w2 * bf_lo(z2) + w3 * bf_lo(z3);
        a1 += w0 * bf_hi(z0) + w1 * bf_hi(z1) + w2 * bf_hi(z2) + w3 * bf_hi(z3);
    }
    for (; e < end; e++) {
        int s = csr_src[e];
        float w = alpha[e];
        unsigned z = zb[(size_t)s * 64 + l];
        a0 += w * bf_lo(z);
        a1 += w * bf_hi(z);
    }
    float2 bb = *(const float2*)&b2[2 * l];
    float2 o;
    o.x = elu_f(a0 + bb.x);
    o.y = elu_f(a1 + bb.y);
    *(float2*)&h2[(size_t)node * HID + 2 * l] = o;
}

// --- K8: mean-pool + classifier ---
static __device__ __forceinline__ int lower_bound_i(const int* a, int n, int v) {
    int lo = 0, hi = n;
    while (lo < hi) { int mid = (lo + hi) >> 1; if (a[mid] < v) lo = mid + 1; else hi = mid; }
    return lo;
}

__global__ __launch_bounds__(1024) void k_pool(const int* __restrict__ gids, const float* __restrict__ h2,
                                               const float* __restrict__ Wc, const float* __restrict__ bc,
                                               float* __restrict__ out) {
    int g = blockIdx.x;
    int lo = lower_bound_i(gids, N_NODES, g);
    int hi = lower_bound_i(gids, N_NODES, g + 1);
    int j = threadIdx.x & 127;   // feature
    int nn = threadIdx.x >> 7;   // node-slot 0..7
    float s = 0.f;
    for (int n = lo + nn; n < hi; n += 8) s += h2[(size_t)n * HID + j];
    __shared__ float red[1024];
    red[threadIdx.x] = s;
    __syncthreads();
    __shared__ float red2[2][3];
    if (threadIdx.x < 128) {
        float hg = 0.f;
#pragma unroll
        for (int q = 0; q < 8; q++) hg += red[q * 128 + j];
        hg /= fmaxf((float)(hi - lo), 1.f);
        float p0 = hg * Wc[j * 3 + 0];
        float p1 = hg * Wc[j * 3 + 1];
        float p2 = hg * Wc[j * 3 + 2];
        for (int mm = 32; mm >= 1; mm >>= 1) {
            p0 += __shfl_xor(p0, mm); p1 += __shfl_xor(p1, mm); p2 += __shfl_xor(p2, mm);
        }
        if ((threadIdx.x & 63) == 0) {
            int w = threadIdx.x >> 6;
            red2[w][0] = p0; red2[w][1] = p1; red2[w][2] = p2;
        }
    }
    __syncthreads();
    if (threadIdx.x < 3)
        out[g * 3 + threadIdx.x] = red2[0][threadIdx.x] + red2[1][threadIdx.x] + bc[threadIdx.x];
}

extern "C" void kernel_launch(void* const* d_in, const int* in_sizes, int n_in,
                              void* d_out, int out_size, void* d_ws, size_t ws_size,
                              hipStream_t stream) {
    (void)in_sizes; (void)n_in; (void)out_size; (void)ws_size;
    const int* edge_src = (const int*)d_in[0];
    const int* edge_dst = (const int*)d_in[1];
    const int* gids     = (const int*)d_in[2];
    const float* W1  = (const float*)d_in[3];
    const float* al1 = (const float*)d_in[4];
    const float* ar1 = (const float*)d_in[5];
    const float* b1  = (const float*)d_in[6];
    const float* W2  = (const float*)d_in[7];
    const float* al2 = (const float*)d_in[8];
    const float* ar2 = (const float*)d_in[9];
    const float* b2  = (const float*)d_in[10];
    const float* Wc  = (const float*)d_in[11];
    const float* bc  = (const float*)d_in[12];
    float* out = (float*)d_out;

    char* p = (char*)d_ws;
    auto alloc = [&](size_t bytes) -> char* {
        char* r = p;
        p += (bytes + 511) & ~(size_t)511;
        return r;
    };
    int*      dr    = (int*)alloc((size_t)NCLASS * N_NODES * 4);   // privatized counters
    int*      base  = (int*)alloc((size_t)NCLASS * N_NODES * 4);   // per-class CSR bases
    int*      rank  = (int*)alloc((size_t)N_EDGES * 4);            // per-edge within-class rank
    int*      offs  = (int*)alloc((size_t)(N_NODES + 1) * 4);
    int*      P     = (int*)alloc((size_t)SNB * 4);
    int*      P2    = (int*)alloc((size_t)SNB * 4);
    float*    scal  = (float*)alloc(64);
    int*      csr   = (int*)alloc((size_t)N_EDGES * 4);
    int*      deg   = (int*)alloc((size_t)N_NODES * 4);
    float*    t     = (float*)alloc((size_t)N_NODES * 4);
    float*    el2   = (float*)alloc((size_t)N_NODES * 4);
    float*    er2   = (float*)alloc((size_t)N_NODES * 4);
    unsigned* zb    = (unsigned*)alloc((size_t)N_NODES * 64 * 4);  // bf16x2 packed
    float*    h2    = (float*)alloc((size_t)N_NODES * HID * 4);
    float*    al_e  = (float*)rank;  // alias: rank is dead after k_fill, al_e born in k_att2

    hipMemsetAsync(dr, 0, (size_t)NCLASS * N_NODES * 4, stream);

    k_prep<<<1, 64, 0, stream>>>(W1, al1, ar1, scal);
    k_degrank<<<2048, 256, 0, stream>>>(edge_dst, dr, rank);
    k_sum<<<(N_NODES + 255) / 256, 256, 0, stream>>>(dr, deg);
    k_scan_part<<<SNB, 256, 0, stream>>>(deg, P);
    k_scan_p2<<<1, 64, 0, stream>>>(P, P2, offs);
    k_scan_final<<<SNB, 256, 0, stream>>>(deg, P2, offs);
    k_base<<<(N_NODES + 255) / 256, 256, 0, stream>>>(dr, offs, base);
    k_fill<<<2048, 256, 0, stream>>>(edge_src, edge_dst, base, rank, csr);
    k_l1<<<(N_NODES + 3) / 4, 256, 0, stream>>>(deg, offs, csr, scal, t);
    k_gemm<<<(N_NODES + 63) / 64, 256, 0, stream>>>(t, W1, b1, W2, al2, ar2, zb, el2, er2);
    k_att2<<<(N_NODES + 3) / 4, 256, 0, stream>>>(offs, csr, el2, er2, al_e);
    k_agg2<<<(N_NODES + 3) / 4, 256, 0, stream>>>(offs, csr, al_e, zb, b2, h2);
    k_pool<<<N_GRAPHS, 1024, 0, stream>>>(gids, h2, Wc, bc, out);
}